// Round 8
// baseline (227.338 us; speedup 1.0000x reference)
//
#include <hip/hip_runtime.h>

// GATLayer on MI355X — round 8.
//   gemm_y (fused qk + atomic qmax): Y[o][n] = sum_c wm[o][c] x[c][n] (fp16);
//       o0==0 blocks also produce q=(wq.x)*L2E, k=(wk.x)*L2E, atomicMax qmax.
//   gemm_out: out[o][m] = relu(bm[o] + invZ_m * sum_n Y[o][n]*E[m][n])
//       E synthesized into MFMA A-frags; 4-way m-split waves; Ys DOUBLE-
//       BUFFERED (1 barrier/iter); epilogue stores j-outer/i-inner so both
//       64B halves of each 128B line issue adjacently (write-combine).

constexpr int B = 32, C = 512, N = 1024, O = 512;
constexpr float L2E = 1.4426950408889634f;

typedef _Float16 half8 __attribute__((ext_vector_type(8)));
typedef _Float16 half4v __attribute__((ext_vector_type(4)));
typedef _Float16 half2v __attribute__((ext_vector_type(2)));
typedef float f32x4 __attribute__((ext_vector_type(4)));

#if __has_builtin(__builtin_amdgcn_exp2f)
#define EXP2(x) __builtin_amdgcn_exp2f(x)
#else
#define EXP2(x) exp2f(x)
#endif

__device__ __forceinline__ half8 cvt8(float4 a, float4 b) {
  half8 h;
  h[0] = (_Float16)a.x; h[1] = (_Float16)a.y; h[2] = (_Float16)a.z; h[3] = (_Float16)a.w;
  h[4] = (_Float16)b.x; h[5] = (_Float16)b.y; h[6] = (_Float16)b.z; h[7] = (_Float16)b.w;
  return h;
}

// monotone float<->uint for atomicMax over signed floats
__device__ __forceinline__ unsigned fenc(float x) {
  unsigned u = __float_as_uint(x);
  return (u & 0x80000000u) ? ~u : (u ^ 0x80000000u);
}
__device__ __forceinline__ float fdec(unsigned e) {
  unsigned u = (e & 0x80000000u) ? (e ^ 0x80000000u) : ~e;
  return __uint_as_float(u);
}

// ---------------- K1: gemm_y + fused qk + atomic qmax ----------------
// (round-5/7 staging verbatim — known good; only the qmax epilogue is new)
__global__ __launch_bounds__(256) void gemm_y_kernel(const float* __restrict__ x,
    const float* __restrict__ wm, const float* __restrict__ wq,
    const float* __restrict__ wk, float* __restrict__ q, float* __restrict__ k,
    unsigned* __restrict__ qmax_u, _Float16* __restrict__ Yt) {
  __shared__ half2v Xs[16 * 130];                 // (c/2, n): low=even c
  __shared__ __align__(16) _Float16 Ws[128 * 40]; // [o][c] K-major
  __shared__ float mred[4];
  int b  = blockIdx.y;
  int n0 = blockIdx.x * 128;
  int o0 = blockIdx.z * 128;
  int t = threadIdx.x;
  int w = t >> 6, l = t & 63;
  int nw = w >> 1, ow = w & 1;
  int lm = l & 15, q8 = (l >> 4) * 8, q4 = (l >> 4) * 4;

  int cp = t >> 4, ng = t & 15;           // Xs staging: rows 2cp,2cp+1, n=ng*8..+7
  int wrow = t >> 2, woff = (t & 3) * 8;  // Ws staging
  bool doqk = (blockIdx.z == 0);
  float aq[8] = {}, ak[8] = {};

  f32x4 acc[4][4] = {};
  for (int c0 = 0; c0 < C; c0 += 32) {
    const float* xr = x + ((size_t)b * C + c0 + 2 * cp) * N + n0 + ng * 8;
    float4 a0 = *(const float4*)(xr);
    float4 a1 = *(const float4*)(xr + 4);
    float4 b0 = *(const float4*)(xr + N);
    float4 b1 = *(const float4*)(xr + N + 4);
    const float* wr = wm + (size_t)(o0 + wrow) * C + c0 + woff;
    float4 w0 = *(const float4*)(wr);
    float4 w1 = *(const float4*)(wr + 4);
    float4 w2 = *(const float4*)(wr + (size_t)64 * C);
    float4 w3 = *(const float4*)(wr + (size_t)64 * C + 4);

    if (doqk) {
      float2 wq2 = *(const float2*)&wq[c0 + 2 * cp];
      float2 wk2 = *(const float2*)&wk[c0 + 2 * cp];
      aq[0] = fmaf(wq2.x, a0.x, fmaf(wq2.y, b0.x, aq[0]));
      aq[1] = fmaf(wq2.x, a0.y, fmaf(wq2.y, b0.y, aq[1]));
      aq[2] = fmaf(wq2.x, a0.z, fmaf(wq2.y, b0.z, aq[2]));
      aq[3] = fmaf(wq2.x, a0.w, fmaf(wq2.y, b0.w, aq[3]));
      aq[4] = fmaf(wq2.x, a1.x, fmaf(wq2.y, b1.x, aq[4]));
      aq[5] = fmaf(wq2.x, a1.y, fmaf(wq2.y, b1.y, aq[5]));
      aq[6] = fmaf(wq2.x, a1.z, fmaf(wq2.y, b1.z, aq[6]));
      aq[7] = fmaf(wq2.x, a1.w, fmaf(wq2.y, b1.w, aq[7]));
      ak[0] = fmaf(wk2.x, a0.x, fmaf(wk2.y, b0.x, ak[0]));
      ak[1] = fmaf(wk2.x, a0.y, fmaf(wk2.y, b0.y, ak[1]));
      ak[2] = fmaf(wk2.x, a0.z, fmaf(wk2.y, b0.z, ak[2]));
      ak[3] = fmaf(wk2.x, a0.w, fmaf(wk2.y, b0.w, ak[3]));
      ak[4] = fmaf(wk2.x, a1.x, fmaf(wk2.y, b1.x, ak[4]));
      ak[5] = fmaf(wk2.x, a1.y, fmaf(wk2.y, b1.y, ak[5]));
      ak[6] = fmaf(wk2.x, a1.z, fmaf(wk2.y, b1.z, ak[6]));
      ak[7] = fmaf(wk2.x, a1.w, fmaf(wk2.y, b1.w, ak[7]));
    }

    __syncthreads();
    {
      half2v* xp = &Xs[cp * 130 + ng * 8];
      xp[0] = half2v{(_Float16)a0.x, (_Float16)b0.x};
      xp[1] = half2v{(_Float16)a0.y, (_Float16)b0.y};
      xp[2] = half2v{(_Float16)a0.z, (_Float16)b0.z};
      xp[3] = half2v{(_Float16)a0.w, (_Float16)b0.w};
      xp[4] = half2v{(_Float16)a1.x, (_Float16)b1.x};
      xp[5] = half2v{(_Float16)a1.y, (_Float16)b1.y};
      xp[6] = half2v{(_Float16)a1.z, (_Float16)b1.z};
      xp[7] = half2v{(_Float16)a1.w, (_Float16)b1.w};
      *(half8*)&Ws[wrow * 40 + woff]        = cvt8(w0, w1);
      *(half8*)&Ws[(wrow + 64) * 40 + woff] = cvt8(w2, w3);
    }
    __syncthreads();

    half8 af[4], bf[4];
#pragma unroll
    for (int i = 0; i < 4; ++i) {
      int nrow = nw * 64 + i * 16 + lm;
#pragma unroll
      for (int jp = 0; jp < 4; ++jp) {
        half2v p = Xs[(q4 + jp) * 130 + nrow];
        af[i][2 * jp]     = p[0];
        af[i][2 * jp + 1] = p[1];
      }
    }
#pragma unroll
    for (int j = 0; j < 4; ++j)
      bf[j] = *(const half8*)&Ws[(ow * 64 + j * 16 + lm) * 40 + q8];
#pragma unroll
    for (int i = 0; i < 4; ++i)
#pragma unroll
      for (int j = 0; j < 4; ++j)
        acc[i][j] = __builtin_amdgcn_mfma_f32_16x16x32_f16(af[i], bf[j], acc[i][j], 0, 0, 0);
  }

#pragma unroll
  for (int i = 0; i < 4; ++i) {
    int n_b = n0 + nw * 64 + i * 16 + (l >> 4) * 4;
#pragma unroll
    for (int j = 0; j < 4; ++j) {
      int o_c = o0 + ow * 64 + j * 16 + lm;
      half4v h;
      h[0] = (_Float16)acc[i][j][0];
      h[1] = (_Float16)acc[i][j][1];
      h[2] = (_Float16)acc[i][j][2];
      h[3] = (_Float16)acc[i][j][3];
      *(half4v*)&Yt[((size_t)b * O + o_c) * N + n_b] = h;
    }
  }

  if (doqk) {
    float* red = (float*)Ws;  // 16 x (stride 132) floats = 8448 B <= 10240 B
    float qv_final = -1e30f;
    __syncthreads();          // all MFMA fragment reads from Ws done
#pragma unroll
    for (int j = 0; j < 8; ++j) red[cp * 132 + ng * 8 + j] = aq[j];
    __syncthreads();
    if (t < 128) {
      float s = 0.f;
#pragma unroll
      for (int p = 0; p < 16; ++p) s += red[p * 132 + t];
      qv_final = L2E * s;
      q[b * N + n0 + t] = qv_final;
    }
    __syncthreads();
#pragma unroll
    for (int j = 0; j < 8; ++j) red[cp * 132 + ng * 8 + j] = ak[j];
    __syncthreads();
    if (t < 128) {
      float s = 0.f;
#pragma unroll
      for (int p = 0; p < 16; ++p) s += red[p * 132 + t];
      k[b * N + n0 + t] = L2E * s;
    }
    // block max of q -> device atomic (replaces qmax kernel)
    float m = qv_final;
#pragma unroll
    for (int off = 32; off > 0; off >>= 1) m = fmaxf(m, __shfl_down(m, off, 64));
    if ((t & 63) == 0) mred[t >> 6] = m;
    __syncthreads();
    if (t == 0) {
      float bmax = fmaxf(fmaxf(mred[0], mred[1]), fmaxf(mred[2], mred[3]));
      atomicMax(&qmax_u[b], fenc(bmax));
    }
  }
}

// ---------------- K2: gemm_out (double-buffered Ys, 1 barrier/iter) ----------
// Block 128m x 128o. Wave w owns m-rows [32w,32w+32) (i=0,1), ALL 128 o.
__global__ __launch_bounds__(256) void gemm_out_kernel(const _Float16* __restrict__ Yt,
    const float* __restrict__ q, const float* __restrict__ k,
    const unsigned* __restrict__ qmax_u, const float* __restrict__ bm,
    float* __restrict__ out) {
  __shared__ __align__(16) float qs[N];
  __shared__ __align__(16) _Float16 Ys[2][128 * 40];
  __shared__ float izs[128];
  int b  = blockIdx.y;
  int o0 = blockIdx.x * 128;
  int m0 = blockIdx.z * 128;
  int t = threadIdx.x;
  int w = t >> 6, l = t & 63;
  int lm = l & 15, g = l >> 4, q8 = g * 8;

  *(float4*)&qs[t * 4] = *(const float4*)&q[b * N + t * 4];

  float qmv = fdec(qmax_u[b]);
  float k2[2], k3[2];
#pragma unroll
  for (int i = 0; i < 2; ++i) {
    float km = k[b * N + m0 + w * 32 + i * 16 + lm];
    float s0 = qmv + km;
    float M  = fmaxf(s0, 0.01f * s0);
    k2[i] = km - M;
    k3[i] = fmaf(0.01f, km, -M);
  }
  float Zp[2] = {0.f, 0.f};
  int yr = t >> 1, yp = t & 1;
  const _Float16* ysrc = Yt + ((size_t)b * O + o0 + yr) * N + yp * 16;

  // stage slab 0
  {
    half8 y0 = *(const half8*)(ysrc);
    half8 y1 = *(const half8*)(ysrc + 8);
    *(half8*)&Ys[0][yr * 40 + yp * 16]     = y0;
    *(half8*)&Ys[0][yr * 40 + yp * 16 + 8] = y1;
  }
  __syncthreads();  // covers qs + slab 0

  f32x4 acc[2][8] = {};
  for (int it = 0; it < N / 32; ++it) {
    int p = it & 1;
    int n0k = it * 32;
    // prefetch next slab from global (in flight across the whole iter body)
    half8 z0, z1;
    if (it < N / 32 - 1) {
      z0 = *(const half8*)(ysrc + n0k + 32);
      z1 = *(const half8*)(ysrc + n0k + 40);
    }
    // E synthesis for this 32-n slab
    float4 qa = *(const float4*)&qs[n0k + q8];
    float4 qb = *(const float4*)&qs[n0k + q8 + 4];
    float qv[8] = {qa.x, qa.y, qa.z, qa.w, qb.x, qb.y, qb.z, qb.w};
    half8 af[2];
#pragma unroll
    for (int i = 0; i < 2; ++i) {
      float zz = 0.f;
#pragma unroll
      for (int jj = 0; jj < 8; ++jj) {
        float arg = fmaxf(qv[jj] + k2[i], fmaf(0.01f, qv[jj], k3[i]));
        _Float16 eh = (_Float16)EXP2(arg);
        af[i][jj] = eh;
        zz += (float)eh;
      }
      Zp[i] += zz;
    }
    // MFMA from current slab
    half8 bf[8];
#pragma unroll
    for (int j = 0; j < 8; ++j)
      bf[j] = *(const half8*)&Ys[p][(j * 16 + lm) * 40 + q8];
#pragma unroll
    for (int i = 0; i < 2; ++i)
#pragma unroll
      for (int j = 0; j < 8; ++j)
        acc[i][j] = __builtin_amdgcn_mfma_f32_16x16x32_f16(af[i], bf[j], acc[i][j], 0, 0, 0);
    // write next slab into the other buffer (reads of it finished last iter)
    if (it < N / 32 - 1) {
      *(half8*)&Ys[p ^ 1][yr * 40 + yp * 16]     = z0;
      *(half8*)&Ys[p ^ 1][yr * 40 + yp * 16 + 8] = z1;
    }
    __syncthreads();  // single barrier: writes to p^1 + reads of p complete
  }

  // Z across the 4 n-quads (within wave), publish invZ per m-row
#pragma unroll
  for (int i = 0; i < 2; ++i) {
    float z = Zp[i];
    z += __shfl_xor(z, 16, 64);
    z += __shfl_xor(z, 32, 64);
    if (g == 0) izs[w * 32 + i * 16 + lm] = 1.0f / z;
  }
  __syncthreads();

  float iz4v[2][4];
#pragma unroll
  for (int i = 0; i < 2; ++i) {
    float4 iz4 = *(const float4*)&izs[w * 32 + i * 16 + g * 4];
    iz4v[i][0] = iz4.x; iz4v[i][1] = iz4.y; iz4v[i][2] = iz4.z; iz4v[i][3] = iz4.w;
  }
  // j OUTER, i inner: both 64B halves of each 128B out-line issue adjacently
#pragma unroll
  for (int j = 0; j < 8; ++j) {
    int o_c = o0 + j * 16 + lm;
    float bias = bm[o_c];
#pragma unroll
    for (int i = 0; i < 2; ++i) {
      int m_b = m0 + w * 32 + i * 16 + g * 4;
      float4 r;
      r.x = fmaxf(fmaf(acc[i][j][0], iz4v[i][0], bias), 0.f);
      r.y = fmaxf(fmaf(acc[i][j][1], iz4v[i][1], bias), 0.f);
      r.z = fmaxf(fmaf(acc[i][j][2], iz4v[i][2], bias), 0.f);
      r.w = fmaxf(fmaf(acc[i][j][3], iz4v[i][3], bias), 0.f);
      *(float4*)&out[((size_t)b * O + o_c) * N + m_b] = r;
    }
  }
}

extern "C" void kernel_launch(void* const* d_in, const int* in_sizes, int n_in,
                              void* d_out, int out_size, void* d_ws, size_t ws_size,
                              hipStream_t stream) {
  const float* x  = (const float*)d_in[0];
  const float* wq = (const float*)d_in[1];
  const float* wk = (const float*)d_in[2];
  const float* wm = (const float*)d_in[3];
  const float* bm = (const float*)d_in[4];
  float* out = (float*)d_out;

  // ws: q[B*N] | k[B*N] | qmax_u[64] | Yt[B*O*N] fp16   (~32.3 MiB)
  float* q    = (float*)d_ws;
  float* k    = q + B * N;
  unsigned* qmax_u = (unsigned*)(k + B * N);
  _Float16* Yt = (_Float16*)(qmax_u + 64);

  hipMemsetAsync(qmax_u, 0, 64 * sizeof(unsigned), stream);  // fenc-min
  // gemm_y: x-strip (n-tile,b) reused by o-blocks at linear stride 256 (same XCD)
  gemm_y_kernel<<<dim3(N / 128, B, O / 128), 256, 0, stream>>>(x, wm, wq, wk, q, k, qmax_u, Yt);
  // gemm_out: Y-strip (o-tile,b) reused by m-blocks at linear stride 128 (same XCD)
  gemm_out_kernel<<<dim3(O / 128, B, N / 128), 256, 0, stream>>>(Yt, q, k, qmax_u, bm, out);
}

// Round 9
// 216.303 us; speedup vs baseline: 1.0510x; 1.0510x over previous
//
#include <hip/hip_runtime.h>

// GATLayer on MI355X — round 9.
//   wmh_kernel: wm fp32 -> fp16 once (512 KB, L2-resident).
//   gemm_y (fused qk + atomic qmax): Y[o][n] = sum_c wm[o][c] x[c][n] (fp16);
//       B-fragments read DIRECTLY from wmh global (no Ws staging);
//       only x goes through the LDS transpose (half2 c-pair trick, known good).
//   gemm_out: out[o][m] = relu(bm[o] + invZ_m * sum_n Y[o][n]*E[m][n])
//       r7 single-buffer loop + j-outer write-combine stores + Z via MFMA
//       against a ones-vector (consistent with the fp16 E the MFMA consumes).

constexpr int B = 32, C = 512, N = 1024, O = 512;
constexpr float L2E = 1.4426950408889634f;

typedef _Float16 half8 __attribute__((ext_vector_type(8)));
typedef _Float16 half4v __attribute__((ext_vector_type(4)));
typedef _Float16 half2v __attribute__((ext_vector_type(2)));
typedef float f32x4 __attribute__((ext_vector_type(4)));

#if __has_builtin(__builtin_amdgcn_exp2f)
#define EXP2(x) __builtin_amdgcn_exp2f(x)
#else
#define EXP2(x) exp2f(x)
#endif

__device__ __forceinline__ half8 cvt8(float4 a, float4 b) {
  half8 h;
  h[0] = (_Float16)a.x; h[1] = (_Float16)a.y; h[2] = (_Float16)a.z; h[3] = (_Float16)a.w;
  h[4] = (_Float16)b.x; h[5] = (_Float16)b.y; h[6] = (_Float16)b.z; h[7] = (_Float16)b.w;
  return h;
}

// monotone float<->uint for atomicMax over signed floats
__device__ __forceinline__ unsigned fenc(float x) {
  unsigned u = __float_as_uint(x);
  return (u & 0x80000000u) ? ~u : (u ^ 0x80000000u);
}
__device__ __forceinline__ float fdec(unsigned e) {
  unsigned u = (e & 0x80000000u) ? (e ^ 0x80000000u) : ~e;
  return __uint_as_float(u);
}

// ---------------- K0: wm -> fp16 (once) ----------------
__global__ __launch_bounds__(256) void wmh_kernel(const float* __restrict__ wm,
                                                  _Float16* __restrict__ wmh) {
  int i = (blockIdx.x * 256 + threadIdx.x) * 8;
  float4 a = *(const float4*)(wm + i);
  float4 b = *(const float4*)(wm + i + 4);
  *(half8*)(wmh + i) = cvt8(a, b);
}

// ---------------- K1: gemm_y + fused qk + atomic qmax ----------------
// Block 128n x 128o, K=c BK=32. Xs stores c-pairs as half2 (A-frags are b32
// k-pair reads). B-frags straight from wmh global (L2-hot).
__global__ __launch_bounds__(256) void gemm_y_kernel(const float* __restrict__ x,
    const _Float16* __restrict__ wmh, const float* __restrict__ wq,
    const float* __restrict__ wk, float* __restrict__ q, float* __restrict__ k,
    unsigned* __restrict__ qmax_u, _Float16* __restrict__ Yt) {
  __shared__ half2v Xs[16 * 130];                 // (c/2, n): low=even c  8320 B
  __shared__ float mred[4];
  int b  = blockIdx.y;
  int n0 = blockIdx.x * 128;
  int o0 = blockIdx.z * 128;
  int t = threadIdx.x;
  int w = t >> 6, l = t & 63;
  int nw = w >> 1, ow = w & 1;
  int lm = l & 15, q8 = (l >> 4) * 8, q4 = (l >> 4) * 4;

  int cp = t >> 4, ng = t & 15;           // Xs staging: rows 2cp,2cp+1, n=ng*8..+7
  bool doqk = (blockIdx.z == 0);
  float aq[8] = {}, ak[8] = {};

  const _Float16* wb[4];
#pragma unroll
  for (int j = 0; j < 4; ++j)
    wb[j] = wmh + (size_t)(o0 + ow * 64 + j * 16 + lm) * C + q8;

  f32x4 acc[4][4] = {};
  for (int c0 = 0; c0 < C; c0 += 32) {
    const float* xr = x + ((size_t)b * C + c0 + 2 * cp) * N + n0 + ng * 8;
    float4 a0 = *(const float4*)(xr);
    float4 a1 = *(const float4*)(xr + 4);
    float4 b0 = *(const float4*)(xr + N);
    float4 b1 = *(const float4*)(xr + N + 4);
    // B-fragments direct from global (issued early, L2-hot)
    half8 bf[4];
#pragma unroll
    for (int j = 0; j < 4; ++j) bf[j] = *(const half8*)(wb[j] + c0);

    if (doqk) {
      float2 wq2 = *(const float2*)&wq[c0 + 2 * cp];
      float2 wk2 = *(const float2*)&wk[c0 + 2 * cp];
      aq[0] = fmaf(wq2.x, a0.x, fmaf(wq2.y, b0.x, aq[0]));
      aq[1] = fmaf(wq2.x, a0.y, fmaf(wq2.y, b0.y, aq[1]));
      aq[2] = fmaf(wq2.x, a0.z, fmaf(wq2.y, b0.z, aq[2]));
      aq[3] = fmaf(wq2.x, a0.w, fmaf(wq2.y, b0.w, aq[3]));
      aq[4] = fmaf(wq2.x, a1.x, fmaf(wq2.y, b1.x, aq[4]));
      aq[5] = fmaf(wq2.x, a1.y, fmaf(wq2.y, b1.y, aq[5]));
      aq[6] = fmaf(wq2.x, a1.z, fmaf(wq2.y, b1.z, aq[6]));
      aq[7] = fmaf(wq2.x, a1.w, fmaf(wq2.y, b1.w, aq[7]));
      ak[0] = fmaf(wk2.x, a0.x, fmaf(wk2.y, b0.x, ak[0]));
      ak[1] = fmaf(wk2.x, a0.y, fmaf(wk2.y, b0.y, ak[1]));
      ak[2] = fmaf(wk2.x, a0.z, fmaf(wk2.y, b0.z, ak[2]));
      ak[3] = fmaf(wk2.x, a0.w, fmaf(wk2.y, b0.w, ak[3]));
      ak[4] = fmaf(wk2.x, a1.x, fmaf(wk2.y, b1.x, ak[4]));
      ak[5] = fmaf(wk2.x, a1.y, fmaf(wk2.y, b1.y, ak[5]));
      ak[6] = fmaf(wk2.x, a1.z, fmaf(wk2.y, b1.z, ak[6]));
      ak[7] = fmaf(wk2.x, a1.w, fmaf(wk2.y, b1.w, ak[7]));
    }

    __syncthreads();
    {
      half2v* xp = &Xs[cp * 130 + ng * 8];
      xp[0] = half2v{(_Float16)a0.x, (_Float16)b0.x};
      xp[1] = half2v{(_Float16)a0.y, (_Float16)b0.y};
      xp[2] = half2v{(_Float16)a0.z, (_Float16)b0.z};
      xp[3] = half2v{(_Float16)a0.w, (_Float16)b0.w};
      xp[4] = half2v{(_Float16)a1.x, (_Float16)b1.x};
      xp[5] = half2v{(_Float16)a1.y, (_Float16)b1.y};
      xp[6] = half2v{(_Float16)a1.z, (_Float16)b1.z};
      xp[7] = half2v{(_Float16)a1.w, (_Float16)b1.w};
    }
    __syncthreads();

    half8 af[4];
#pragma unroll
    for (int i = 0; i < 4; ++i) {
      int nrow = nw * 64 + i * 16 + lm;
#pragma unroll
      for (int jp = 0; jp < 4; ++jp) {
        half2v p = Xs[(q4 + jp) * 130 + nrow];
        af[i][2 * jp]     = p[0];
        af[i][2 * jp + 1] = p[1];
      }
    }
#pragma unroll
    for (int i = 0; i < 4; ++i)
#pragma unroll
      for (int j = 0; j < 4; ++j)
        acc[i][j] = __builtin_amdgcn_mfma_f32_16x16x32_f16(af[i], bf[j], acc[i][j], 0, 0, 0);
  }

#pragma unroll
  for (int i = 0; i < 4; ++i) {
    int n_b = n0 + nw * 64 + i * 16 + (l >> 4) * 4;
#pragma unroll
    for (int j = 0; j < 4; ++j) {
      int o_c = o0 + ow * 64 + j * 16 + lm;
      half4v h;
      h[0] = (_Float16)acc[i][j][0];
      h[1] = (_Float16)acc[i][j][1];
      h[2] = (_Float16)acc[i][j][2];
      h[3] = (_Float16)acc[i][j][3];
      *(half4v*)&Yt[((size_t)b * O + o_c) * N + n_b] = h;
    }
  }

  if (doqk) {
    float* red = (float*)Xs;  // stride 130 floats; 15*130+127 = 2077 < 2080 ✓
    float qv_final = -1e30f;
    __syncthreads();          // all Xs fragment reads done
#pragma unroll
    for (int j = 0; j < 8; ++j) red[cp * 130 + ng * 8 + j] = aq[j];
    __syncthreads();
    if (t < 128) {
      float s = 0.f;
#pragma unroll
      for (int p = 0; p < 16; ++p) s += red[p * 130 + t];
      qv_final = L2E * s;
      q[b * N + n0 + t] = qv_final;
    }
    __syncthreads();
#pragma unroll
    for (int j = 0; j < 8; ++j) red[cp * 130 + ng * 8 + j] = ak[j];
    __syncthreads();
    if (t < 128) {
      float s = 0.f;
#pragma unroll
      for (int p = 0; p < 16; ++p) s += red[p * 130 + t];
      k[b * N + n0 + t] = L2E * s;
    }
    // block max of q -> device atomic
    float m = qv_final;
#pragma unroll
    for (int off = 32; off > 0; off >>= 1) m = fmaxf(m, __shfl_down(m, off, 64));
    if ((t & 63) == 0) mred[t >> 6] = m;
    __syncthreads();
    if (t == 0) {
      float bmax = fmaxf(fmaxf(mred[0], mred[1]), fmaxf(mred[2], mred[3]));
      atomicMax(&qmax_u[b], fenc(bmax));
    }
  }
}

// ---------------- K2: gemm_out (r7 loop, Z via ones-MFMA, j-outer stores) ----
// Block 128m x 128o. Wave w owns m-rows [32w,32w+32) (i=0,1), ALL 128 o.
__global__ __launch_bounds__(256) void gemm_out_kernel(const _Float16* __restrict__ Yt,
    const float* __restrict__ q, const float* __restrict__ k,
    const unsigned* __restrict__ qmax_u, const float* __restrict__ bm,
    float* __restrict__ out) {
  __shared__ __align__(16) float qs[N];
  __shared__ __align__(16) _Float16 Ys[128 * 40];
  __shared__ float izs[128];
  int b  = blockIdx.y;
  int o0 = blockIdx.x * 128;
  int m0 = blockIdx.z * 128;
  int t = threadIdx.x;
  int w = t >> 6, l = t & 63;
  int lm = l & 15, g = l >> 4, q8 = g * 8;

  *(float4*)&qs[t * 4] = *(const float4*)&q[b * N + t * 4];

  float qmv = fdec(qmax_u[b]);
  float k2[2], k3[2];
#pragma unroll
  for (int i = 0; i < 2; ++i) {
    float km = k[b * N + m0 + w * 32 + i * 16 + lm];
    float s0 = qmv + km;
    float M  = fmaxf(s0, 0.01f * s0);
    k2[i] = km - M;
    k3[i] = fmaf(0.01f, km, -M);
  }
  half8 ones;
#pragma unroll
  for (int jj = 0; jj < 8; ++jj) ones[jj] = (_Float16)1.0f;
  f32x4 acc_z[2] = {};
  int yr = t >> 1, yp = t & 1;
  const _Float16* ysrc = Yt + ((size_t)b * O + o0 + yr) * N + yp * 16;
  __syncthreads();  // qs staged

  f32x4 acc[2][8] = {};
  for (int n0k = 0; n0k < N; n0k += 32) {
    half8 y0 = *(const half8*)(ysrc + n0k);
    half8 y1 = *(const half8*)(ysrc + n0k + 8);
    float4 qa = *(const float4*)&qs[n0k + q8];
    float4 qb = *(const float4*)&qs[n0k + q8 + 4];
    float qv[8] = {qa.x, qa.y, qa.z, qa.w, qb.x, qb.y, qb.z, qb.w};
    half8 af[2];
#pragma unroll
    for (int i = 0; i < 2; ++i) {
#pragma unroll
      for (int jj = 0; jj < 8; ++jj) {
        float arg = fmaxf(qv[jj] + k2[i], fmaf(0.01f, qv[jj], k3[i]));
        af[i][jj] = (_Float16)EXP2(arg);
      }
      acc_z[i] = __builtin_amdgcn_mfma_f32_16x16x32_f16(af[i], ones, acc_z[i], 0, 0, 0);
    }
    __syncthreads();  // previous bf reads done
    *(half8*)&Ys[yr * 40 + yp * 16]     = y0;
    *(half8*)&Ys[yr * 40 + yp * 16 + 8] = y1;
    __syncthreads();

    half8 bf[8];
#pragma unroll
    for (int j = 0; j < 8; ++j)
      bf[j] = *(const half8*)&Ys[(j * 16 + lm) * 40 + q8];
#pragma unroll
    for (int i = 0; i < 2; ++i)
#pragma unroll
      for (int j = 0; j < 8; ++j)
        acc[i][j] = __builtin_amdgcn_mfma_f32_16x16x32_f16(af[i], bf[j], acc[i][j], 0, 0, 0);
  }

  // acc_z D-layout: lane (g,lm) reg r holds Z[row g*4+r] (any column).
  if (lm == 0) {
#pragma unroll
    for (int i = 0; i < 2; ++i) {
#pragma unroll
      for (int r = 0; r < 4; ++r)
        izs[w * 32 + i * 16 + g * 4 + r] = 1.0f / acc_z[i][r];
    }
  }
  __syncthreads();

  float iz4v[2][4];
#pragma unroll
  for (int i = 0; i < 2; ++i) {
    float4 iz4 = *(const float4*)&izs[w * 32 + i * 16 + g * 4];
    iz4v[i][0] = iz4.x; iz4v[i][1] = iz4.y; iz4v[i][2] = iz4.z; iz4v[i][3] = iz4.w;
  }
  // j OUTER, i inner: both 64B halves of each 128B out-line issue adjacently
#pragma unroll
  for (int j = 0; j < 8; ++j) {
    int o_c = o0 + j * 16 + lm;
    float bias = bm[o_c];
#pragma unroll
    for (int i = 0; i < 2; ++i) {
      int m_b = m0 + w * 32 + i * 16 + g * 4;
      float4 r;
      r.x = fmaxf(fmaf(acc[i][j][0], iz4v[i][0], bias), 0.f);
      r.y = fmaxf(fmaf(acc[i][j][1], iz4v[i][1], bias), 0.f);
      r.z = fmaxf(fmaf(acc[i][j][2], iz4v[i][2], bias), 0.f);
      r.w = fmaxf(fmaf(acc[i][j][3], iz4v[i][3], bias), 0.f);
      *(float4*)&out[((size_t)b * O + o_c) * N + m_b] = r;
    }
  }
}

extern "C" void kernel_launch(void* const* d_in, const int* in_sizes, int n_in,
                              void* d_out, int out_size, void* d_ws, size_t ws_size,
                              hipStream_t stream) {
  const float* x  = (const float*)d_in[0];
  const float* wq = (const float*)d_in[1];
  const float* wk = (const float*)d_in[2];
  const float* wm = (const float*)d_in[3];
  const float* bm = (const float*)d_in[4];
  float* out = (float*)d_out;

  // ws: q[B*N] | k[B*N] | qmax_u[64] | wmh[O*C] f16 | Yt[B*O*N] f16  (~33 MiB)
  float* q    = (float*)d_ws;
  float* k    = q + B * N;
  unsigned* qmax_u = (unsigned*)(k + B * N);
  _Float16* wmh = (_Float16*)(qmax_u + 64);
  _Float16* Yt  = wmh + (size_t)O * C;

  hipMemsetAsync(qmax_u, 0, 64 * sizeof(unsigned), stream);  // fenc-min
  wmh_kernel<<<dim3(O * C / (256 * 8)), 256, 0, stream>>>(wm, wmh);
  // gemm_y: x-strip (n-tile,b) reused by o-blocks at linear stride 256 (same XCD)
  gemm_y_kernel<<<dim3(N / 128, B, O / 128), 256, 0, stream>>>(x, wmh, wq, wk, q, k, qmax_u, Yt);
  // gemm_out: Y-strip (o-tile,b) reused by m-blocks at linear stride 128 (same XCD)
  gemm_out_kernel<<<dim3(O / 128, B, N / 128), 256, 0, stream>>>(Yt, q, k, qmax_u, bm, out);
}

// Round 10
// 210.405 us; speedup vs baseline: 1.0805x; 1.0280x over previous
//
#include <hip/hip_runtime.h>

// GATLayer on MI355X — round 10.
//   wmh_kernel: wm fp32 -> fp16 once; also zero-inits qmax_u (no memset node).
//   gemm_y (fused qk + atomic qmax): r9 verbatim (known good).
//   gemm_out: 512-thread blocks, o-tile=256 (E redundancy 4x->2x; per-lane
//       exp count halves). Wave w owns m-strip [16w,16w+16), all 256 o.
//       Z via ones-MFMA (same fp16-consistent arithmetic as r9).

constexpr int B = 32, C = 512, N = 1024, O = 512;
constexpr float L2E = 1.4426950408889634f;

typedef _Float16 half8 __attribute__((ext_vector_type(8)));
typedef _Float16 half4v __attribute__((ext_vector_type(4)));
typedef _Float16 half2v __attribute__((ext_vector_type(2)));
typedef float f32x4 __attribute__((ext_vector_type(4)));

#if __has_builtin(__builtin_amdgcn_exp2f)
#define EXP2(x) __builtin_amdgcn_exp2f(x)
#else
#define EXP2(x) exp2f(x)
#endif

__device__ __forceinline__ half8 cvt8(float4 a, float4 b) {
  half8 h;
  h[0] = (_Float16)a.x; h[1] = (_Float16)a.y; h[2] = (_Float16)a.z; h[3] = (_Float16)a.w;
  h[4] = (_Float16)b.x; h[5] = (_Float16)b.y; h[6] = (_Float16)b.z; h[7] = (_Float16)b.w;
  return h;
}

// monotone float<->uint for atomicMax over signed floats
__device__ __forceinline__ unsigned fenc(float x) {
  unsigned u = __float_as_uint(x);
  return (u & 0x80000000u) ? ~u : (u ^ 0x80000000u);
}
__device__ __forceinline__ float fdec(unsigned e) {
  unsigned u = (e & 0x80000000u) ? (e ^ 0x80000000u) : ~e;
  return __uint_as_float(u);
}

// ---------------- K0: wm -> fp16 (once) + qmax_u init ----------------
__global__ __launch_bounds__(256) void wmh_kernel(const float* __restrict__ wm,
                                                  _Float16* __restrict__ wmh,
                                                  unsigned* __restrict__ qmax_u) {
  int i = (blockIdx.x * 256 + threadIdx.x) * 8;
  float4 a = *(const float4*)(wm + i);
  float4 b = *(const float4*)(wm + i + 4);
  *(half8*)(wmh + i) = cvt8(a, b);
  if (blockIdx.x == 0 && threadIdx.x < 64) qmax_u[threadIdx.x] = 0u;  // fenc-min
}

// ---------------- K1: gemm_y + fused qk + atomic qmax (r9 verbatim) ----------
__global__ __launch_bounds__(256) void gemm_y_kernel(const float* __restrict__ x,
    const _Float16* __restrict__ wmh, const float* __restrict__ wq,
    const float* __restrict__ wk, float* __restrict__ q, float* __restrict__ k,
    unsigned* __restrict__ qmax_u, _Float16* __restrict__ Yt) {
  __shared__ half2v Xs[16 * 130];                 // (c/2, n): low=even c  8320 B
  __shared__ float mred[4];
  int b  = blockIdx.y;
  int n0 = blockIdx.x * 128;
  int o0 = blockIdx.z * 128;
  int t = threadIdx.x;
  int w = t >> 6, l = t & 63;
  int nw = w >> 1, ow = w & 1;
  int lm = l & 15, q8 = (l >> 4) * 8, q4 = (l >> 4) * 4;

  int cp = t >> 4, ng = t & 15;           // Xs staging: rows 2cp,2cp+1, n=ng*8..+7
  bool doqk = (blockIdx.z == 0);
  float aq[8] = {}, ak[8] = {};

  const _Float16* wb[4];
#pragma unroll
  for (int j = 0; j < 4; ++j)
    wb[j] = wmh + (size_t)(o0 + ow * 64 + j * 16 + lm) * C + q8;

  f32x4 acc[4][4] = {};
  for (int c0 = 0; c0 < C; c0 += 32) {
    const float* xr = x + ((size_t)b * C + c0 + 2 * cp) * N + n0 + ng * 8;
    float4 a0 = *(const float4*)(xr);
    float4 a1 = *(const float4*)(xr + 4);
    float4 b0 = *(const float4*)(xr + N);
    float4 b1 = *(const float4*)(xr + N + 4);
    half8 bf[4];
#pragma unroll
    for (int j = 0; j < 4; ++j) bf[j] = *(const half8*)(wb[j] + c0);

    if (doqk) {
      float2 wq2 = *(const float2*)&wq[c0 + 2 * cp];
      float2 wk2 = *(const float2*)&wk[c0 + 2 * cp];
      aq[0] = fmaf(wq2.x, a0.x, fmaf(wq2.y, b0.x, aq[0]));
      aq[1] = fmaf(wq2.x, a0.y, fmaf(wq2.y, b0.y, aq[1]));
      aq[2] = fmaf(wq2.x, a0.z, fmaf(wq2.y, b0.z, aq[2]));
      aq[3] = fmaf(wq2.x, a0.w, fmaf(wq2.y, b0.w, aq[3]));
      aq[4] = fmaf(wq2.x, a1.x, fmaf(wq2.y, b1.x, aq[4]));
      aq[5] = fmaf(wq2.x, a1.y, fmaf(wq2.y, b1.y, aq[5]));
      aq[6] = fmaf(wq2.x, a1.z, fmaf(wq2.y, b1.z, aq[6]));
      aq[7] = fmaf(wq2.x, a1.w, fmaf(wq2.y, b1.w, aq[7]));
      ak[0] = fmaf(wk2.x, a0.x, fmaf(wk2.y, b0.x, ak[0]));
      ak[1] = fmaf(wk2.x, a0.y, fmaf(wk2.y, b0.y, ak[1]));
      ak[2] = fmaf(wk2.x, a0.z, fmaf(wk2.y, b0.z, ak[2]));
      ak[3] = fmaf(wk2.x, a0.w, fmaf(wk2.y, b0.w, ak[3]));
      ak[4] = fmaf(wk2.x, a1.x, fmaf(wk2.y, b1.x, ak[4]));
      ak[5] = fmaf(wk2.x, a1.y, fmaf(wk2.y, b1.y, ak[5]));
      ak[6] = fmaf(wk2.x, a1.z, fmaf(wk2.y, b1.z, ak[6]));
      ak[7] = fmaf(wk2.x, a1.w, fmaf(wk2.y, b1.w, ak[7]));
    }

    __syncthreads();
    {
      half2v* xp = &Xs[cp * 130 + ng * 8];
      xp[0] = half2v{(_Float16)a0.x, (_Float16)b0.x};
      xp[1] = half2v{(_Float16)a0.y, (_Float16)b0.y};
      xp[2] = half2v{(_Float16)a0.z, (_Float16)b0.z};
      xp[3] = half2v{(_Float16)a0.w, (_Float16)b0.w};
      xp[4] = half2v{(_Float16)a1.x, (_Float16)b1.x};
      xp[5] = half2v{(_Float16)a1.y, (_Float16)b1.y};
      xp[6] = half2v{(_Float16)a1.z, (_Float16)b1.z};
      xp[7] = half2v{(_Float16)a1.w, (_Float16)b1.w};
    }
    __syncthreads();

    half8 af[4];
#pragma unroll
    for (int i = 0; i < 4; ++i) {
      int nrow = nw * 64 + i * 16 + lm;
#pragma unroll
      for (int jp = 0; jp < 4; ++jp) {
        half2v p = Xs[(q4 + jp) * 130 + nrow];
        af[i][2 * jp]     = p[0];
        af[i][2 * jp + 1] = p[1];
      }
    }
#pragma unroll
    for (int i = 0; i < 4; ++i)
#pragma unroll
      for (int j = 0; j < 4; ++j)
        acc[i][j] = __builtin_amdgcn_mfma_f32_16x16x32_f16(af[i], bf[j], acc[i][j], 0, 0, 0);
  }

#pragma unroll
  for (int i = 0; i < 4; ++i) {
    int n_b = n0 + nw * 64 + i * 16 + (l >> 4) * 4;
#pragma unroll
    for (int j = 0; j < 4; ++j) {
      int o_c = o0 + ow * 64 + j * 16 + lm;
      half4v h;
      h[0] = (_Float16)acc[i][j][0];
      h[1] = (_Float16)acc[i][j][1];
      h[2] = (_Float16)acc[i][j][2];
      h[3] = (_Float16)acc[i][j][3];
      *(half4v*)&Yt[((size_t)b * O + o_c) * N + n_b] = h;
    }
  }

  if (doqk) {
    float* red = (float*)Xs;  // stride 130 floats; 15*130+127 = 2077 < 2080 ✓
    float qv_final = -1e30f;
    __syncthreads();          // all Xs fragment reads done
#pragma unroll
    for (int j = 0; j < 8; ++j) red[cp * 130 + ng * 8 + j] = aq[j];
    __syncthreads();
    if (t < 128) {
      float s = 0.f;
#pragma unroll
      for (int p = 0; p < 16; ++p) s += red[p * 130 + t];
      qv_final = L2E * s;
      q[b * N + n0 + t] = qv_final;
    }
    __syncthreads();
#pragma unroll
    for (int j = 0; j < 8; ++j) red[cp * 130 + ng * 8 + j] = ak[j];
    __syncthreads();
    if (t < 128) {
      float s = 0.f;
#pragma unroll
      for (int p = 0; p < 16; ++p) s += red[p * 130 + t];
      k[b * N + n0 + t] = L2E * s;
    }
    float m = qv_final;
#pragma unroll
    for (int off = 32; off > 0; off >>= 1) m = fmaxf(m, __shfl_down(m, off, 64));
    if ((t & 63) == 0) mred[t >> 6] = m;
    __syncthreads();
    if (t == 0) {
      float bmax = fmaxf(fmaxf(mred[0], mred[1]), fmaxf(mred[2], mred[3]));
      atomicMax(&qmax_u[b], fenc(bmax));
    }
  }
}

// ---------------- K2: gemm_out — 512 threads, o-tile 256, m-tile 128 ---------
// Wave w (0..7) owns m-rows [m0+16w, m0+16w+16), all 256 o (j=0..15).
// E synthesized into A-frags (8 exps/lane/iter); Z via ones-MFMA.
__global__ __launch_bounds__(512) void gemm_out_kernel(const _Float16* __restrict__ Yt,
    const float* __restrict__ q, const float* __restrict__ k,
    const unsigned* __restrict__ qmax_u, const float* __restrict__ bm,
    float* __restrict__ out) {
  __shared__ __align__(16) float qs[N];            // 4 KB
  __shared__ __align__(16) _Float16 Ys[256 * 40];  // 20 KB
  __shared__ float izs[128];
  int b  = blockIdx.y;
  int o0 = blockIdx.x * 256;
  int m0 = blockIdx.z * 128;
  int t = threadIdx.x;
  int w = t >> 6, l = t & 63;
  int lm = l & 15, g = l >> 4, q8 = g * 8;

  *(float2*)&qs[t * 2] = *(const float2*)&q[b * N + t * 2];

  float qmv = fdec(qmax_u[b]);
  float km = k[b * N + m0 + w * 16 + lm];
  float s0 = qmv + km;
  float M  = fmaxf(s0, 0.01f * s0);
  float k2 = km - M;
  float k3 = fmaf(0.01f, km, -M);

  half8 ones;
#pragma unroll
  for (int jj = 0; jj < 8; ++jj) ones[jj] = (_Float16)1.0f;
  f32x4 acc_z = {};
  int yr = t >> 1, yp = t & 1;                       // rows 0..255
  const _Float16* ysrc = Yt + ((size_t)b * O + o0 + yr) * N + yp * 16;
  __syncthreads();  // qs staged

  f32x4 acc[16] = {};
  for (int n0k = 0; n0k < N; n0k += 32) {
    half8 y0 = *(const half8*)(ysrc + n0k);
    half8 y1 = *(const half8*)(ysrc + n0k + 8);
    float4 qa = *(const float4*)&qs[n0k + q8];
    float4 qb = *(const float4*)&qs[n0k + q8 + 4];
    float qv[8] = {qa.x, qa.y, qa.z, qa.w, qb.x, qb.y, qb.z, qb.w};
    half8 af;
#pragma unroll
    for (int jj = 0; jj < 8; ++jj) {
      float arg = fmaxf(qv[jj] + k2, fmaf(0.01f, qv[jj], k3));
      af[jj] = (_Float16)EXP2(arg);
    }
    acc_z = __builtin_amdgcn_mfma_f32_16x16x32_f16(af, ones, acc_z, 0, 0, 0);

    __syncthreads();  // previous bf reads done
    *(half8*)&Ys[yr * 40 + yp * 16]     = y0;
    *(half8*)&Ys[yr * 40 + yp * 16 + 8] = y1;
    __syncthreads();

#pragma unroll
    for (int j = 0; j < 16; ++j) {
      half8 bf = *(const half8*)&Ys[(j * 16 + lm) * 40 + q8];
      acc[j] = __builtin_amdgcn_mfma_f32_16x16x32_f16(af, bf, acc[j], 0, 0, 0);
    }
  }

  // acc_z D-layout: lane (g,lm) reg r holds Z[m-row g*4+r] (any col).
  if (lm == 0) {
#pragma unroll
    for (int r = 0; r < 4; ++r)
      izs[w * 16 + g * 4 + r] = 1.0f / acc_z[r];
  }
  __syncthreads();

  float4 iz4 = *(const float4*)&izs[w * 16 + g * 4];
  // j outer: adjacent 64B m-segments per o-row issue together (write-combine)
#pragma unroll
  for (int j = 0; j < 16; ++j) {
    int o_c = o0 + j * 16 + lm;
    float bias = bm[o_c];
    int m_b = m0 + w * 16 + g * 4;
    float4 r;
    r.x = fmaxf(fmaf(acc[j][0], iz4.x, bias), 0.f);
    r.y = fmaxf(fmaf(acc[j][1], iz4.y, bias), 0.f);
    r.z = fmaxf(fmaf(acc[j][2], iz4.z, bias), 0.f);
    r.w = fmaxf(fmaf(acc[j][3], iz4.w, bias), 0.f);
    *(float4*)&out[((size_t)b * O + o_c) * N + m_b] = r;
  }
}

extern "C" void kernel_launch(void* const* d_in, const int* in_sizes, int n_in,
                              void* d_out, int out_size, void* d_ws, size_t ws_size,
                              hipStream_t stream) {
  const float* x  = (const float*)d_in[0];
  const float* wq = (const float*)d_in[1];
  const float* wk = (const float*)d_in[2];
  const float* wm = (const float*)d_in[3];
  const float* bm = (const float*)d_in[4];
  float* out = (float*)d_out;

  // ws: q[B*N] | k[B*N] | qmax_u[64] | wmh[O*C] f16 | Yt[B*O*N] f16  (~33 MiB)
  float* q    = (float*)d_ws;
  float* k    = q + B * N;
  unsigned* qmax_u = (unsigned*)(k + B * N);
  _Float16* wmh = (_Float16*)(qmax_u + 64);
  _Float16* Yt  = wmh + (size_t)O * C;

  wmh_kernel<<<dim3(O * C / (256 * 8)), 256, 0, stream>>>(wm, wmh, qmax_u);
  // gemm_y: x-strip (n-tile,b) reused by o-blocks at linear stride 256 (same XCD)
  gemm_y_kernel<<<dim3(N / 128, B, O / 128), 256, 0, stream>>>(x, wmh, wq, wk, q, k, qmax_u, Yt);
  // gemm_out: Y-strip (o-tile,b) reused by 8 m-blocks at linear stride 64 (same XCD)
  gemm_out_kernel<<<dim3(O / 256, B, N / 128), 512, 0, stream>>>(Yt, q, k, qmax_u, bm, out);
}

// Round 11
// 209.085 us; speedup vs baseline: 1.0873x; 1.0063x over previous
//
#include <hip/hip_runtime.h>

// GATLayer on MI355X — round 11.
//   wmh_kernel: wm fp32 -> fp16 once; zero-inits qmax_u.
//   gemm_y: r10 math verbatim, restructured as software-pipelined dbuf
//       (Xs double-buffer, 1 barrier/iter, x+wmh prefetched one iter ahead).
//       q,k,Yt bitwise-identical to r10.
//   gemm_out: 32x32x16 MFMA (2x FLOP per LDS byte), block 256m x 256o
//       (grid 256 = 1 block/CU), Ys double-buffered w/ reg prefetch,
//       1 barrier/slab. E synthesized into 32x32 A-frags; Z via ones-MFMA.

constexpr int B = 32, C = 512, N = 1024, O = 512;
constexpr float L2E = 1.4426950408889634f;

typedef _Float16 half8 __attribute__((ext_vector_type(8)));
typedef _Float16 half4v __attribute__((ext_vector_type(4)));
typedef _Float16 half2v __attribute__((ext_vector_type(2)));
typedef float f32x4 __attribute__((ext_vector_type(4)));
typedef float f32x16 __attribute__((ext_vector_type(16)));

#if __has_builtin(__builtin_amdgcn_exp2f)
#define EXP2(x) __builtin_amdgcn_exp2f(x)
#else
#define EXP2(x) exp2f(x)
#endif

__device__ __forceinline__ half8 cvt8(float4 a, float4 b) {
  half8 h;
  h[0] = (_Float16)a.x; h[1] = (_Float16)a.y; h[2] = (_Float16)a.z; h[3] = (_Float16)a.w;
  h[4] = (_Float16)b.x; h[5] = (_Float16)b.y; h[6] = (_Float16)b.z; h[7] = (_Float16)b.w;
  return h;
}

__device__ __forceinline__ unsigned fenc(float x) {
  unsigned u = __float_as_uint(x);
  return (u & 0x80000000u) ? ~u : (u ^ 0x80000000u);
}
__device__ __forceinline__ float fdec(unsigned e) {
  unsigned u = (e & 0x80000000u) ? (e ^ 0x80000000u) : ~e;
  return __uint_as_float(u);
}

// ---------------- K0: wm -> fp16 (once) + qmax_u init ----------------
__global__ __launch_bounds__(256) void wmh_kernel(const float* __restrict__ wm,
                                                  _Float16* __restrict__ wmh,
                                                  unsigned* __restrict__ qmax_u) {
  int i = (blockIdx.x * 256 + threadIdx.x) * 8;
  float4 a = *(const float4*)(wm + i);
  float4 b = *(const float4*)(wm + i + 4);
  *(half8*)(wmh + i) = cvt8(a, b);
  if (blockIdx.x == 0 && threadIdx.x < 64) qmax_u[threadIdx.x] = 0u;  // fenc-min
}

// ---------------- K1: gemm_y — dbuf Xs, 1 barrier/iter, prefetch -------------
__global__ __launch_bounds__(256) void gemm_y_kernel(const float* __restrict__ x,
    const _Float16* __restrict__ wmh, const float* __restrict__ wq,
    const float* __restrict__ wk, float* __restrict__ q, float* __restrict__ k,
    unsigned* __restrict__ qmax_u, _Float16* __restrict__ Yt) {
  __shared__ half2v Xs[2][16 * 130];              // (c/2, n) dbuf  16640 B
  __shared__ float mred[4];
  int b  = blockIdx.y;
  int n0 = blockIdx.x * 128;
  int o0 = blockIdx.z * 128;
  int t = threadIdx.x;
  int w = t >> 6, l = t & 63;
  int nw = w >> 1, ow = w & 1;
  int lm = l & 15, q8 = (l >> 4) * 8, q4 = (l >> 4) * 4;

  int cp = t >> 4, ng = t & 15;
  bool doqk = (blockIdx.z == 0);
  float aq[8] = {}, ak[8] = {};

  const _Float16* wb[4];
#pragma unroll
  for (int j = 0; j < 4; ++j)
    wb[j] = wmh + (size_t)(o0 + ow * 64 + j * 16 + lm) * C + q8;
  const float* xbase = x + ((size_t)b * C + 2 * cp) * N + n0 + ng * 8;

  // ---- prologue: load + qk + stage chunk 0 into Xs[0]
  float4 a0 = *(const float4*)(xbase);
  float4 a1 = *(const float4*)(xbase + 4);
  float4 b0 = *(const float4*)(xbase + N);
  float4 b1 = *(const float4*)(xbase + N + 4);
  half8 bf[4];
#pragma unroll
  for (int j = 0; j < 4; ++j) bf[j] = *(const half8*)(wb[j]);

  if (doqk) {
    float2 wq2 = *(const float2*)&wq[2 * cp];
    float2 wk2 = *(const float2*)&wk[2 * cp];
    aq[0] = fmaf(wq2.x, a0.x, fmaf(wq2.y, b0.x, aq[0]));
    aq[1] = fmaf(wq2.x, a0.y, fmaf(wq2.y, b0.y, aq[1]));
    aq[2] = fmaf(wq2.x, a0.z, fmaf(wq2.y, b0.z, aq[2]));
    aq[3] = fmaf(wq2.x, a0.w, fmaf(wq2.y, b0.w, aq[3]));
    aq[4] = fmaf(wq2.x, a1.x, fmaf(wq2.y, b1.x, aq[4]));
    aq[5] = fmaf(wq2.x, a1.y, fmaf(wq2.y, b1.y, aq[5]));
    aq[6] = fmaf(wq2.x, a1.z, fmaf(wq2.y, b1.z, aq[6]));
    aq[7] = fmaf(wq2.x, a1.w, fmaf(wq2.y, b1.w, aq[7]));
    ak[0] = fmaf(wk2.x, a0.x, fmaf(wk2.y, b0.x, ak[0]));
    ak[1] = fmaf(wk2.x, a0.y, fmaf(wk2.y, b0.y, ak[1]));
    ak[2] = fmaf(wk2.x, a0.z, fmaf(wk2.y, b0.z, ak[2]));
    ak[3] = fmaf(wk2.x, a0.w, fmaf(wk2.y, b0.w, ak[3]));
    ak[4] = fmaf(wk2.x, a1.x, fmaf(wk2.y, b1.x, ak[4]));
    ak[5] = fmaf(wk2.x, a1.y, fmaf(wk2.y, b1.y, ak[5]));
    ak[6] = fmaf(wk2.x, a1.z, fmaf(wk2.y, b1.z, ak[6]));
    ak[7] = fmaf(wk2.x, a1.w, fmaf(wk2.y, b1.w, ak[7]));
  }
  {
    half2v* xp = &Xs[0][cp * 130 + ng * 8];
    xp[0] = half2v{(_Float16)a0.x, (_Float16)b0.x};
    xp[1] = half2v{(_Float16)a0.y, (_Float16)b0.y};
    xp[2] = half2v{(_Float16)a0.z, (_Float16)b0.z};
    xp[3] = half2v{(_Float16)a0.w, (_Float16)b0.w};
    xp[4] = half2v{(_Float16)a1.x, (_Float16)b1.x};
    xp[5] = half2v{(_Float16)a1.y, (_Float16)b1.y};
    xp[6] = half2v{(_Float16)a1.z, (_Float16)b1.z};
    xp[7] = half2v{(_Float16)a1.w, (_Float16)b1.w};
  }
  __syncthreads();

  f32x4 acc[4][4] = {};
  for (int it = 0; it < 16; ++it) {
    int p = it & 1;
    // prefetch next chunk (x + wmh) — in flight across the MFMA block
    float4 na0, na1, nb0, nb1;
    half8 nbf[4];
    if (it < 15) {
      int c1 = (it + 1) * 32;
      const float* xr = xbase + (size_t)c1 * N;
      na0 = *(const float4*)(xr);
      na1 = *(const float4*)(xr + 4);
      nb0 = *(const float4*)(xr + N);
      nb1 = *(const float4*)(xr + N + 4);
#pragma unroll
      for (int j = 0; j < 4; ++j) nbf[j] = *(const half8*)(wb[j] + c1);
    }
    // compute on Xs[p] with current bf
    half8 af[4];
#pragma unroll
    for (int i = 0; i < 4; ++i) {
      int nrow = nw * 64 + i * 16 + lm;
#pragma unroll
      for (int jp = 0; jp < 4; ++jp) {
        half2v pr = Xs[p][(q4 + jp) * 130 + nrow];
        af[i][2 * jp]     = pr[0];
        af[i][2 * jp + 1] = pr[1];
      }
    }
#pragma unroll
    for (int i = 0; i < 4; ++i)
#pragma unroll
      for (int j = 0; j < 4; ++j)
        acc[i][j] = __builtin_amdgcn_mfma_f32_16x16x32_f16(af[i], bf[j], acc[i][j], 0, 0, 0);

    if (it < 15) {
      int c1 = (it + 1) * 32;
      if (doqk) {
        float2 wq2 = *(const float2*)&wq[c1 + 2 * cp];
        float2 wk2 = *(const float2*)&wk[c1 + 2 * cp];
        aq[0] = fmaf(wq2.x, na0.x, fmaf(wq2.y, nb0.x, aq[0]));
        aq[1] = fmaf(wq2.x, na0.y, fmaf(wq2.y, nb0.y, aq[1]));
        aq[2] = fmaf(wq2.x, na0.z, fmaf(wq2.y, nb0.z, aq[2]));
        aq[3] = fmaf(wq2.x, na0.w, fmaf(wq2.y, nb0.w, aq[3]));
        aq[4] = fmaf(wq2.x, na1.x, fmaf(wq2.y, nb1.x, aq[4]));
        aq[5] = fmaf(wq2.x, na1.y, fmaf(wq2.y, nb1.y, aq[5]));
        aq[6] = fmaf(wq2.x, na1.z, fmaf(wq2.y, nb1.z, aq[6]));
        aq[7] = fmaf(wq2.x, na1.w, fmaf(wq2.y, nb1.w, aq[7]));
        ak[0] = fmaf(wk2.x, na0.x, fmaf(wk2.y, nb0.x, ak[0]));
        ak[1] = fmaf(wk2.x, na0.y, fmaf(wk2.y, nb0.y, ak[1]));
        ak[2] = fmaf(wk2.x, na0.z, fmaf(wk2.y, nb0.z, ak[2]));
        ak[3] = fmaf(wk2.x, na0.w, fmaf(wk2.y, nb0.w, ak[3]));
        ak[4] = fmaf(wk2.x, na1.x, fmaf(wk2.y, nb1.x, ak[4]));
        ak[5] = fmaf(wk2.x, na1.y, fmaf(wk2.y, nb1.y, ak[5]));
        ak[6] = fmaf(wk2.x, na1.z, fmaf(wk2.y, nb1.z, ak[6]));
        ak[7] = fmaf(wk2.x, na1.w, fmaf(wk2.y, nb1.w, ak[7]));
      }
      half2v* xp = &Xs[p ^ 1][cp * 130 + ng * 8];
      xp[0] = half2v{(_Float16)na0.x, (_Float16)nb0.x};
      xp[1] = half2v{(_Float16)na0.y, (_Float16)nb0.y};
      xp[2] = half2v{(_Float16)na0.z, (_Float16)nb0.z};
      xp[3] = half2v{(_Float16)na0.w, (_Float16)nb0.w};
      xp[4] = half2v{(_Float16)na1.x, (_Float16)nb1.x};
      xp[5] = half2v{(_Float16)na1.y, (_Float16)nb1.y};
      xp[6] = half2v{(_Float16)na1.z, (_Float16)nb1.z};
      xp[7] = half2v{(_Float16)na1.w, (_Float16)nb1.w};
#pragma unroll
      for (int j = 0; j < 4; ++j) bf[j] = nbf[j];
    }
    __syncthreads();
  }

#pragma unroll
  for (int i = 0; i < 4; ++i) {
    int n_b = n0 + nw * 64 + i * 16 + (l >> 4) * 4;
#pragma unroll
    for (int j = 0; j < 4; ++j) {
      int o_c = o0 + ow * 64 + j * 16 + lm;
      half4v h;
      h[0] = (_Float16)acc[i][j][0];
      h[1] = (_Float16)acc[i][j][1];
      h[2] = (_Float16)acc[i][j][2];
      h[3] = (_Float16)acc[i][j][3];
      *(half4v*)&Yt[((size_t)b * O + o_c) * N + n_b] = h;
    }
  }

  if (doqk) {
    float* red = (float*)Xs;  // 16 x stride-130 floats within buffer 0
    float qv_final = -1e30f;
    __syncthreads();
#pragma unroll
    for (int j = 0; j < 8; ++j) red[cp * 130 + ng * 8 + j] = aq[j];
    __syncthreads();
    if (t < 128) {
      float s = 0.f;
#pragma unroll
      for (int p = 0; p < 16; ++p) s += red[p * 130 + t];
      qv_final = L2E * s;
      q[b * N + n0 + t] = qv_final;
    }
    __syncthreads();
#pragma unroll
    for (int j = 0; j < 8; ++j) red[cp * 130 + ng * 8 + j] = ak[j];
    __syncthreads();
    if (t < 128) {
      float s = 0.f;
#pragma unroll
      for (int p = 0; p < 16; ++p) s += red[p * 130 + t];
      k[b * N + n0 + t] = L2E * s;
    }
    float m = qv_final;
#pragma unroll
    for (int off = 32; off > 0; off >>= 1) m = fmaxf(m, __shfl_down(m, off, 64));
    if ((t & 63) == 0) mred[t >> 6] = m;
    __syncthreads();
    if (t == 0) {
      float bmax = fmaxf(fmaxf(mred[0], mred[1]), fmaxf(mred[2], mred[3]));
      atomicMax(&qmax_u[b], fenc(bmax));
    }
  }
}

// ---------------- K2: gemm_out — 32x32x16 MFMA, dbuf Ys, 1 barrier/slab ------
// Block 256m x 256o, 512 thr. Wave w owns m-strip [32w,32w+32), all 256 o.
// A = E (synthesized: row m = l&31, k = (l>>5)*8+j), B = Y from LDS.
__global__ __launch_bounds__(512) void gemm_out_kernel(const _Float16* __restrict__ Yt,
    const float* __restrict__ q, const float* __restrict__ k,
    const unsigned* __restrict__ qmax_u, const float* __restrict__ bm,
    float* __restrict__ out) {
  __shared__ __align__(16) float qs[N];             // 4 KB
  __shared__ __align__(16) _Float16 Ys[2][256 * 40];// 40 KB
  __shared__ float izs[256];
  int b  = blockIdx.y;
  int o0 = blockIdx.x * 256;
  int m0 = blockIdx.z * 256;
  int t = threadIdx.x;
  int w = t >> 6, l = t & 63;
  int ml = l & 31, g2 = l >> 5;

  *(float2*)&qs[t * 2] = *(const float2*)&q[b * N + t * 2];

  float qmv = fdec(qmax_u[b]);
  float km = k[b * N + m0 + w * 32 + ml];
  float s0 = qmv + km;
  float M  = fmaxf(s0, 0.01f * s0);
  float kc2 = km - M;
  float kc3 = fmaf(0.01f, km, -M);

  half8 ones;
#pragma unroll
  for (int jj = 0; jj < 8; ++jj) ones[jj] = (_Float16)1.0f;
  f32x16 acc_z = {};
  int yr = t >> 1, yp = t & 1;
  const _Float16* ysrc = Yt + ((size_t)b * O + o0 + yr) * N + yp * 16;

  // prologue: stage slab 0
  {
    half8 z0 = *(const half8*)(ysrc);
    half8 z1 = *(const half8*)(ysrc + 8);
    *(half8*)&Ys[0][yr * 40 + yp * 16]     = z0;
    *(half8*)&Ys[0][yr * 40 + yp * 16 + 8] = z1;
  }
  __syncthreads();  // qs + slab 0

  f32x16 acc[8] = {};
  for (int it = 0; it < N / 32; ++it) {
    int p = it & 1;
    int n0k = it * 32;
    half8 z0, z1;
    if (it < N / 32 - 1) {  // prefetch next slab; drains after the MFMA body
      z0 = *(const half8*)(ysrc + n0k + 32);
      z1 = *(const half8*)(ysrc + n0k + 40);
    }
#pragma unroll
    for (int kh = 0; kh < 2; ++kh) {
      float4 qa = *(const float4*)&qs[n0k + kh * 16 + g2 * 8];
      float4 qb = *(const float4*)&qs[n0k + kh * 16 + g2 * 8 + 4];
      float qv[8] = {qa.x, qa.y, qa.z, qa.w, qb.x, qb.y, qb.z, qb.w};
      half8 af;
#pragma unroll
      for (int jj = 0; jj < 8; ++jj) {
        float arg = fmaxf(qv[jj] + kc2, fmaf(0.01f, qv[jj], kc3));
        af[jj] = (_Float16)EXP2(arg);
      }
      acc_z = __builtin_amdgcn_mfma_f32_32x32x16_f16(af, ones, acc_z, 0, 0, 0);
#pragma unroll
      for (int s = 0; s < 8; ++s) {
        half8 bf = *(const half8*)&Ys[p][(s * 32 + ml) * 40 + kh * 16 + g2 * 8];
        acc[s] = __builtin_amdgcn_mfma_f32_32x32x16_f16(af, bf, acc[s], 0, 0, 0);
      }
    }
    if (it < N / 32 - 1) {
      *(half8*)&Ys[p ^ 1][yr * 40 + yp * 16]     = z0;
      *(half8*)&Ys[p ^ 1][yr * 40 + yp * 16 + 8] = z1;
    }
    __syncthreads();  // single barrier: p reads + p^1 writes complete
  }

  // acc_z D: row = (reg&3) + 8*(reg>>2) + 4*g2, col = l&31 (all cols equal)
  if (ml == 0) {
#pragma unroll
    for (int rq = 0; rq < 4; ++rq)
#pragma unroll
      for (int r = 0; r < 4; ++r)
        izs[w * 32 + r + 8 * rq + 4 * g2] = 1.0f / acc_z[rq * 4 + r];
  }
  __syncthreads();

  float4 izv[4];
#pragma unroll
  for (int rq = 0; rq < 4; ++rq)
    izv[rq] = *(const float4*)&izs[w * 32 + 8 * rq + 4 * g2];

  // s outer: per o-row, the rq stores are adjacent (write-combine)
#pragma unroll
  for (int s = 0; s < 8; ++s) {
    int o_c = o0 + s * 32 + ml;
    float bias = bm[o_c];
#pragma unroll
    for (int rq = 0; rq < 4; ++rq) {
      int m_b = m0 + w * 32 + 8 * rq + 4 * g2;
      float4 r;
      r.x = fmaxf(fmaf(acc[s][rq * 4 + 0], izv[rq].x, bias), 0.f);
      r.y = fmaxf(fmaf(acc[s][rq * 4 + 1], izv[rq].y, bias), 0.f);
      r.z = fmaxf(fmaf(acc[s][rq * 4 + 2], izv[rq].z, bias), 0.f);
      r.w = fmaxf(fmaf(acc[s][rq * 4 + 3], izv[rq].w, bias), 0.f);
      *(float4*)&out[((size_t)b * O + o_c) * N + m_b] = r;
    }
  }
}

extern "C" void kernel_launch(void* const* d_in, const int* in_sizes, int n_in,
                              void* d_out, int out_size, void* d_ws, size_t ws_size,
                              hipStream_t stream) {
  const float* x  = (const float*)d_in[0];
  const float* wq = (const float*)d_in[1];
  const float* wk = (const float*)d_in[2];
  const float* wm = (const float*)d_in[3];
  const float* bm = (const float*)d_in[4];
  float* out = (float*)d_out;

  // ws: q[B*N] | k[B*N] | qmax_u[64] | wmh[O*C] f16 | Yt[B*O*N] f16  (~33 MiB)
  float* q    = (float*)d_ws;
  float* k    = q + B * N;
  unsigned* qmax_u = (unsigned*)(k + B * N);
  _Float16* wmh = (_Float16*)(qmax_u + 64);
  _Float16* Yt  = wmh + (size_t)O * C;

  wmh_kernel<<<dim3(O * C / (256 * 8)), 256, 0, stream>>>(wm, wmh, qmax_u);
  gemm_y_kernel<<<dim3(N / 128, B, O / 128), 256, 0, stream>>>(x, wmh, wq, wk, q, k, qmax_u, Yt);
  gemm_out_kernel<<<dim3(O / 256, B, N / 256), 512, 0, stream>>>(Yt, q, k, qmax_u, bm, out);
}